// Round 1
// baseline (3729.670 us; speedup 1.0000x reference)
//
#include <hip/hip_runtime.h>
#include <math.h>

// Problem constants (from reference)
constexpr int NN = 20000;   // nodes
constexpr int NE = 320000;  // edges

// ---------------- degree / norm ----------------
__global__ void deg_count_kernel(const int* __restrict__ src, const int* __restrict__ dst,
                                 float* __restrict__ dsrc, float* __restrict__ ddst, int nE) {
  int e = blockIdx.x * blockDim.x + threadIdx.x;
  if (e < nE) {
    atomicAdd(dsrc + src[e], 1.0f);
    atomicAdd(ddst + dst[e], 1.0f);
  }
}

__global__ void rsqrt_kernel(float* __restrict__ d, int n) {
  int i = blockIdx.x * blockDim.x + threadIdx.x;
  if (i < n) d[i] = rsqrtf(fmaxf(d[i], 1.0f));
}

// ---------------- out[i][:] = in[i][:] * s[i] ----------------
template <int F>
__global__ void row_scale_kernel(const float* __restrict__ in, const float* __restrict__ s,
                                 float* __restrict__ out, int n) {
  constexpr int F4 = F / 4;
  int t = blockIdx.x * blockDim.x + threadIdx.x;
  if (t < n * F4) {
    int i = t / F4;  // compile-time F4 -> shift
    float4 v = reinterpret_cast<const float4*>(in)[t];
    float sc = s[i];
    v.x *= sc; v.y *= sc; v.z *= sc; v.w *= sc;
    reinterpret_cast<float4*>(out)[t] = v;
  }
}

// ---------------- out[dst[e]][:] += in[src[e]][:] (scatter-atomic) ----------------
template <int F>
__global__ void seg_add_kernel(const float* __restrict__ h, const int* __restrict__ src,
                               const int* __restrict__ dst, float* __restrict__ out, int nE) {
  constexpr int F4 = F / 4;
  int t = blockIdx.x * blockDim.x + threadIdx.x;
  if (t >= nE * F4) return;
  int e = t / F4;
  int j = (t - e * F4) * 4;
  int sR = src[e], dR = dst[e];
  float4 v = *reinterpret_cast<const float4*>(h + (size_t)sR * F + j);
  float* o = out + (size_t)dR * F + j;
  atomicAdd(o + 0, v.x);
  atomicAdd(o + 1, v.y);
  atomicAdd(o + 2, v.z);
  atomicAdd(o + 3, v.w);
}

// ---------------- post-aggregation: v = agg*nd + b; optional writeback; sigmoid out ----
template <int F>
__global__ void post_kernel(float* __restrict__ agg, const float* __restrict__ nd,
                            const float* __restrict__ b, float* __restrict__ sig_out,
                            int n, int write_back) {
  constexpr int F4 = F / 4;
  int t = blockIdx.x * blockDim.x + threadIdx.x;
  if (t >= n * F4) return;
  int i = t / F4;
  int j4 = (t - i * F4) * 4;
  float4 v = reinterpret_cast<float4*>(agg)[t];
  float s = nd[i];
  float4 bb = *reinterpret_cast<const float4*>(b + j4);
  v.x = v.x * s + bb.x;
  v.y = v.y * s + bb.y;
  v.z = v.z * s + bb.z;
  v.w = v.w * s + bb.w;
  if (write_back) reinterpret_cast<float4*>(agg)[t] = v;
  float4 o;
  o.x = 1.0f / (1.0f + expf(-v.x));
  o.y = 1.0f / (1.0f + expf(-v.y));
  o.z = 1.0f / (1.0f + expf(-v.z));
  o.w = 1.0f / (1.0f + expf(-v.w));
  reinterpret_cast<float4*>(sig_out)[t] = o;
}

// ---------------- fp32 tiled GEMM: C[M,N] = epi(A[M,K] @ W[K,N]) ----------------
// epi: v = acc * rowscale[r] (if rowscale) + bias[c] (if bias); relu (if do_relu)
constexpr int BM = 64, BN = 64, BK = 16;

__global__ __launch_bounds__(256) void gemm_kernel(
    const float* __restrict__ A, const float* __restrict__ W, float* __restrict__ C,
    int M, int K, int N, const float* __restrict__ rowscale,
    const float* __restrict__ bias, int do_relu) {
  __shared__ float As[BK][BM];  // A-tile transposed
  __shared__ float Bs[BK][BN];
  const int tid = threadIdx.x;
  const int bm = blockIdx.y * BM;
  const int bn = blockIdx.x * BN;
  const int tx = tid & 15;  // col group
  const int ty = tid >> 4;  // row group
  const int aRow = tid >> 2;
  const int aCol = (tid & 3) << 2;
  const int bRow = tid >> 4;
  const int bCol = (tid & 15) << 2;
  float acc[4][4] = {};
  const bool aOk = (bm + aRow) < M;       // K % 16 == 0 always here
  const bool bOk = (bn + bCol) < N;       // N % 4 == 0 always here
  const float* aPtr = A + (size_t)(bm + aRow) * K + aCol;
  const float* bPtr = W + (size_t)bRow * N + bn + bCol;

  for (int k0 = 0; k0 < K; k0 += BK) {
    float4 av = make_float4(0.f, 0.f, 0.f, 0.f);
    if (aOk) av = *reinterpret_cast<const float4*>(aPtr + k0);
    float4 bv = make_float4(0.f, 0.f, 0.f, 0.f);
    if (bOk) bv = *reinterpret_cast<const float4*>(bPtr + (size_t)k0 * N);
    As[aCol + 0][aRow] = av.x;
    As[aCol + 1][aRow] = av.y;
    As[aCol + 2][aRow] = av.z;
    As[aCol + 3][aRow] = av.w;
    *reinterpret_cast<float4*>(&Bs[bRow][bCol]) = bv;
    __syncthreads();
#pragma unroll
    for (int k = 0; k < BK; ++k) {
      float4 a4 = *reinterpret_cast<const float4*>(&As[k][ty << 2]);
      float4 b4 = *reinterpret_cast<const float4*>(&Bs[k][tx << 2]);
      float ar[4] = {a4.x, a4.y, a4.z, a4.w};
      float br[4] = {b4.x, b4.y, b4.z, b4.w};
#pragma unroll
      for (int i = 0; i < 4; ++i)
#pragma unroll
        for (int j = 0; j < 4; ++j) acc[i][j] = fmaf(ar[i], br[j], acc[i][j]);
    }
    __syncthreads();
  }

#pragma unroll
  for (int i = 0; i < 4; ++i) {
    int r = bm + (ty << 2) + i;
    if (r >= M) continue;
    float rs = rowscale ? rowscale[r] : 1.0f;
    int c0 = bn + (tx << 2);
    if (c0 < N) {  // N % 4 == 0 and c0 % 4 == 0 -> whole float4 in or out
      float4 v;
      v.x = acc[i][0] * rs;
      v.y = acc[i][1] * rs;
      v.z = acc[i][2] * rs;
      v.w = acc[i][3] * rs;
      if (bias) {
        float4 bb = *reinterpret_cast<const float4*>(bias + c0);
        v.x += bb.x; v.y += bb.y; v.z += bb.z; v.w += bb.w;
      }
      if (do_relu) {
        v.x = fmaxf(v.x, 0.f); v.y = fmaxf(v.y, 0.f);
        v.z = fmaxf(v.z, 0.f); v.w = fmaxf(v.w, 0.f);
      }
      *reinterpret_cast<float4*>(C + (size_t)r * N + c0) = v;
    }
  }
}

extern "C" void kernel_launch(void* const* d_in, const int* in_sizes, int n_in,
                              void* d_out, int out_size, void* d_ws, size_t ws_size,
                              hipStream_t stream) {
  const float* x  = (const float*)d_in[0];
  const int* src  = (const int*)d_in[1];
  const int* dst  = (const int*)d_in[2];
  const float* W1 = (const float*)d_in[3];
  const float* b1 = (const float*)d_in[4];
  const float* W2 = (const float*)d_in[5];
  const float* b2 = (const float*)d_in[6];
  const float* W3 = (const float*)d_in[7];
  const float* b3 = (const float*)d_in[8];
  const float* W4 = (const float*)d_in[9];
  const float* b4 = (const float*)d_in[10];

  float* out_enc = (float*)d_out;                  // [NN,128]
  float* out_dec = out_enc + (size_t)NN * 128;     // [NN,256]

  // workspace layout (125.6 MB total)
  float* ws    = (float*)d_ws;
  float* ns    = ws;                               // [NN]  src-side (out-degree) norm
  float* nd    = ns + NN;                          // [NN]  dst-side (in-degree) norm
  float* A800  = nd + NN;                          // [NN*800]
  float* B256a = A800 + (size_t)NN * 800;          // [NN*256]
  float* B256b = B256a + (size_t)NN * 256;         // [NN*256]
  float* C128a = B256b + (size_t)NN * 256;         // [NN*128]
  float* C128b = C128a + (size_t)NN * 128;         // [NN*128]

  // ---- degrees & norms (recomputed every call: deterministic, poison-safe) ----
  hipMemsetAsync(ns, 0, 2 * NN * sizeof(float), stream);
  deg_count_kernel<<<(NE + 255) / 256, 256, 0, stream>>>(src, dst, ns, nd, NE);
  rsqrt_kernel<<<(2 * NN + 255) / 256, 256, 0, stream>>>(ns, 2 * NN);

  // ---- L1: agg-first (256 -> 800), relu ----
  row_scale_kernel<256><<<(NN * 64 + 255) / 256, 256, 0, stream>>>(x, ns, B256a, NN);
  hipMemsetAsync(B256b, 0, (size_t)NN * 256 * sizeof(float), stream);
  seg_add_kernel<256><<<(NE * 64 + 255) / 256, 256, 0, stream>>>(B256a, src, dst, B256b, NE);
  {
    dim3 g((800 + BN - 1) / BN, (NN + BM - 1) / BM);
    gemm_kernel<<<g, 256, 0, stream>>>(B256b, W1, A800, NN, 256, 800, nd, b1, 1);
  }

  // ---- L2: matmul-first (800 -> 128), h2 kept, encoded = sigmoid(h2) ----
  {
    dim3 g((128 + BN - 1) / BN, (NN + BM - 1) / BM);
    gemm_kernel<<<g, 256, 0, stream>>>(A800, W2, C128a, NN, 800, 128, ns, nullptr, 0);
  }
  hipMemsetAsync(C128b, 0, (size_t)NN * 128 * sizeof(float), stream);
  seg_add_kernel<128><<<(NE * 32 + 255) / 256, 256, 0, stream>>>(C128a, src, dst, C128b, NE);
  post_kernel<128><<<(NN * 32 + 255) / 256, 256, 0, stream>>>(C128b, nd, b2, out_enc, NN, 1);

  // ---- L3: agg-first (128 -> 800) on pre-sigmoid h2, relu ----
  row_scale_kernel<128><<<(NN * 32 + 255) / 256, 256, 0, stream>>>(C128b, ns, C128a, NN);
  hipMemsetAsync(C128b, 0, (size_t)NN * 128 * sizeof(float), stream);
  seg_add_kernel<128><<<(NE * 32 + 255) / 256, 256, 0, stream>>>(C128a, src, dst, C128b, NE);
  {
    dim3 g((800 + BN - 1) / BN, (NN + BM - 1) / BM);
    gemm_kernel<<<g, 256, 0, stream>>>(C128b, W3, A800, NN, 128, 800, nd, b3, 1);
  }

  // ---- L4: matmul-first (800 -> 256), decoded = sigmoid ----
  {
    dim3 g((256 + BN - 1) / BN, (NN + BM - 1) / BM);
    gemm_kernel<<<g, 256, 0, stream>>>(A800, W4, B256a, NN, 800, 256, ns, nullptr, 0);
  }
  hipMemsetAsync(B256b, 0, (size_t)NN * 256 * sizeof(float), stream);
  seg_add_kernel<256><<<(NE * 64 + 255) / 256, 256, 0, stream>>>(B256a, src, dst, B256b, NE);
  post_kernel<256><<<(NN * 64 + 255) / 256, 256, 0, stream>>>(B256b, nd, b4, out_dec, NN, 0);
}

// Round 2
// 623.943 us; speedup vs baseline: 5.9776x; 5.9776x over previous
//
#include <hip/hip_runtime.h>
#include <math.h>

// Problem constants (from reference)
constexpr int NN = 20000;   // nodes
constexpr int NE = 320000;  // edges

// ---------------- degree count (int) ----------------
__global__ void deg_count_kernel(const int* __restrict__ src, const int* __restrict__ dst,
                                 int* __restrict__ degs, int* __restrict__ degd, int nE) {
  int e = blockIdx.x * blockDim.x + threadIdx.x;
  if (e < nE) {
    atomicAdd(degs + src[e], 1);
    atomicAdd(degd + dst[e], 1);
  }
}

__global__ void norm_kernel(const int* __restrict__ degs, const int* __restrict__ degd,
                            float* __restrict__ ns, float* __restrict__ nd, int n) {
  int i = blockIdx.x * blockDim.x + threadIdx.x;
  if (i < n) {
    ns[i] = rsqrtf(fmaxf((float)degs[i], 1.0f));
    nd[i] = rsqrtf(fmaxf((float)degd[i], 1.0f));
  }
}

// ---------------- single-block exclusive scan of degd -> rowptr[NN+1] ----------------
__global__ __launch_bounds__(1024) void scan_kernel(const int* __restrict__ deg,
                                                    int* __restrict__ rowptr, int n) {
  constexpr int T = 1024;
  const int ITEMS = (n + T - 1) / T;
  __shared__ int sums[T];
  int t = threadIdx.x;
  int base = t * ITEMS;
  int s = 0;
  for (int i = 0; i < ITEMS; ++i) {
    int idx = base + i;
    if (idx < n) s += deg[idx];
  }
  sums[t] = s;
  __syncthreads();
  for (int off = 1; off < T; off <<= 1) {
    int v = (t >= off) ? sums[t - off] : 0;
    __syncthreads();
    sums[t] += v;
    __syncthreads();
  }
  int ex = (t == 0) ? 0 : sums[t - 1];
  for (int i = 0; i < ITEMS; ++i) {
    int idx = base + i;
    if (idx < n) {
      rowptr[idx] = ex;
      ex += deg[idx];
    }
  }
  if (t == 0) rowptr[n] = sums[T - 1];
}

// ---------------- CSR fill: col[rowptr[dst]+cursor++] = src ----------------
__global__ void csr_fill_kernel(const int* __restrict__ src, const int* __restrict__ dst,
                                const int* __restrict__ rowptr, int* __restrict__ cursor,
                                int* __restrict__ col, int nE) {
  int e = blockIdx.x * blockDim.x + threadIdx.x;
  if (e < nE) {
    int d = dst[e];
    int p = atomicAdd(cursor + d, 1);
    col[rowptr[d] + p] = src[e];
  }
}

// ---------------- CSR gather aggregation, optionally fused with norm/bias/sigmoid ----
// out[i][:] = SUM_{e in [rowptr[i],rowptr[i+1])} in[col[e]][:] * (SCALE_SRC ? sSrc[col[e]] : 1)
// EPI==0: write raw sum to out.
// EPI==1: v = sum*sDst[i] + bias; write v to out AND sigmoid(v) to out2.
// EPI==2: v = sum*sDst[i] + bias; write sigmoid(v) to out2 only.
template <int F, int SCALE_SRC, int EPI>
__global__ __launch_bounds__(256) void gather_kernel(
    const float* __restrict__ in, const float* __restrict__ sSrc,
    const int* __restrict__ rowptr, const int* __restrict__ col,
    const float* __restrict__ sDst, const float* __restrict__ bias,
    float* __restrict__ out, float* __restrict__ out2, int n) {
  constexpr int F4 = F / 4;
  constexpr int NPB = 256 / F4;  // nodes per block
  int tid = threadIdx.x;
  int node = blockIdx.x * NPB + tid / F4;
  int j = tid % F4;
  if (node >= n) return;
  int e0 = rowptr[node], e1 = rowptr[node + 1];
  const float4* in4 = reinterpret_cast<const float4*>(in);
  float4 acc = make_float4(0.f, 0.f, 0.f, 0.f);
  for (int e = e0; e < e1; ++e) {
    int c = col[e];
    float4 v = in4[(size_t)c * F4 + j];
    if (SCALE_SRC) {
      float sc = sSrc[c];
      v.x *= sc; v.y *= sc; v.z *= sc; v.w *= sc;
    }
    acc.x += v.x; acc.y += v.y; acc.z += v.z; acc.w += v.w;
  }
  if (EPI == 0) {
    reinterpret_cast<float4*>(out)[(size_t)node * F4 + j] = acc;
    return;
  }
  float sd = sDst[node];
  float4 bb = reinterpret_cast<const float4*>(bias)[j];
  acc.x = acc.x * sd + bb.x;
  acc.y = acc.y * sd + bb.y;
  acc.z = acc.z * sd + bb.z;
  acc.w = acc.w * sd + bb.w;
  if (EPI == 1) reinterpret_cast<float4*>(out)[(size_t)node * F4 + j] = acc;
  float4 o;
  o.x = 1.0f / (1.0f + expf(-acc.x));
  o.y = 1.0f / (1.0f + expf(-acc.y));
  o.z = 1.0f / (1.0f + expf(-acc.z));
  o.w = 1.0f / (1.0f + expf(-acc.w));
  reinterpret_cast<float4*>(out2)[(size_t)node * F4 + j] = o;
}

// ---------------- fp32 tiled GEMM: C[M,N] = epi(A[M,K] @ W[K,N]) ----------------
// epi: v = acc * rowscale[r] (if rowscale) + bias[c] (if bias); relu (if do_relu)
constexpr int BM = 64, BN = 64, BK = 16;

__global__ __launch_bounds__(256) void gemm_kernel(
    const float* __restrict__ A, const float* __restrict__ W, float* __restrict__ C,
    int M, int K, int N, const float* __restrict__ rowscale,
    const float* __restrict__ bias, int do_relu) {
  __shared__ float As[BK][BM];  // A-tile transposed
  __shared__ float Bs[BK][BN];
  const int tid = threadIdx.x;
  const int bm = blockIdx.y * BM;
  const int bn = blockIdx.x * BN;
  const int tx = tid & 15;  // col group
  const int ty = tid >> 4;  // row group
  const int aRow = tid >> 2;
  const int aCol = (tid & 3) << 2;
  const int bRow = tid >> 4;
  const int bCol = (tid & 15) << 2;
  float acc[4][4] = {};
  const bool aOk = (bm + aRow) < M;
  const bool bOk = (bn + bCol) < N;
  const float* aPtr = A + (size_t)(bm + aRow) * K + aCol;
  const float* bPtr = W + (size_t)bRow * N + bn + bCol;

  for (int k0 = 0; k0 < K; k0 += BK) {
    float4 av = make_float4(0.f, 0.f, 0.f, 0.f);
    if (aOk) av = *reinterpret_cast<const float4*>(aPtr + k0);
    float4 bv = make_float4(0.f, 0.f, 0.f, 0.f);
    if (bOk) bv = *reinterpret_cast<const float4*>(bPtr + (size_t)k0 * N);
    As[aCol + 0][aRow] = av.x;
    As[aCol + 1][aRow] = av.y;
    As[aCol + 2][aRow] = av.z;
    As[aCol + 3][aRow] = av.w;
    *reinterpret_cast<float4*>(&Bs[bRow][bCol]) = bv;
    __syncthreads();
#pragma unroll
    for (int k = 0; k < BK; ++k) {
      float4 a4 = *reinterpret_cast<const float4*>(&As[k][ty << 2]);
      float4 b4 = *reinterpret_cast<const float4*>(&Bs[k][tx << 2]);
      float ar[4] = {a4.x, a4.y, a4.z, a4.w};
      float br[4] = {b4.x, b4.y, b4.z, b4.w};
#pragma unroll
      for (int i = 0; i < 4; ++i)
#pragma unroll
        for (int j = 0; j < 4; ++j) acc[i][j] = fmaf(ar[i], br[j], acc[i][j]);
    }
    __syncthreads();
  }

#pragma unroll
  for (int i = 0; i < 4; ++i) {
    int r = bm + (ty << 2) + i;
    if (r >= M) continue;
    float rs = rowscale ? rowscale[r] : 1.0f;
    int c0 = bn + (tx << 2);
    if (c0 < N) {
      float4 v;
      v.x = acc[i][0] * rs;
      v.y = acc[i][1] * rs;
      v.z = acc[i][2] * rs;
      v.w = acc[i][3] * rs;
      if (bias) {
        float4 bb = *reinterpret_cast<const float4*>(bias + c0);
        v.x += bb.x; v.y += bb.y; v.z += bb.z; v.w += bb.w;
      }
      if (do_relu) {
        v.x = fmaxf(v.x, 0.f); v.y = fmaxf(v.y, 0.f);
        v.z = fmaxf(v.z, 0.f); v.w = fmaxf(v.w, 0.f);
      }
      *reinterpret_cast<float4*>(C + (size_t)r * N + c0) = v;
    }
  }
}

extern "C" void kernel_launch(void* const* d_in, const int* in_sizes, int n_in,
                              void* d_out, int out_size, void* d_ws, size_t ws_size,
                              hipStream_t stream) {
  const float* x  = (const float*)d_in[0];
  const int* src  = (const int*)d_in[1];
  const int* dst  = (const int*)d_in[2];
  const float* W1 = (const float*)d_in[3];
  const float* b1 = (const float*)d_in[4];
  const float* W2 = (const float*)d_in[5];
  const float* b2 = (const float*)d_in[6];
  const float* W3 = (const float*)d_in[7];
  const float* b3 = (const float*)d_in[8];
  const float* W4 = (const float*)d_in[9];
  const float* b4 = (const float*)d_in[10];

  float* out_enc = (float*)d_out;                  // [NN,128]
  float* out_dec = out_enc + (size_t)NN * 128;     // [NN,256]

  // ---- workspace layout (~107 MB) ----
  float* ws    = (float*)d_ws;
  float* ns    = ws;                               // [NN]
  float* nd    = ns + NN;                          // [NN]
  float* A800  = nd + NN;                          // [NN*800]
  float* G256  = A800 + (size_t)NN * 800;          // [NN*256]  (L1 gather out; L4 gemm out)
  float* T128a = G256 + (size_t)NN * 256;          // [NN*128]
  float* T128b = T128a + (size_t)NN * 128;         // [NN*128]
  int* degs    = (int*)(T128b + (size_t)NN * 128); // [NN]
  int* degd    = degs + NN;                        // [NN]
  int* cursor  = degd + NN;                        // [NN]
  int* rowptr  = cursor + NN;                      // [NN+1]
  int* col     = rowptr + NN + 1;                  // [NE]

  // ---- CSR build + norms (recomputed every call: deterministic given inputs) ----
  hipMemsetAsync(degs, 0, 3 * NN * sizeof(int), stream);  // degs, degd, cursor
  deg_count_kernel<<<(NE + 255) / 256, 256, 0, stream>>>(src, dst, degs, degd, NE);
  norm_kernel<<<(NN + 255) / 256, 256, 0, stream>>>(degs, degd, ns, nd, NN);
  scan_kernel<<<1, 1024, 0, stream>>>(degd, rowptr, NN);
  csr_fill_kernel<<<(NE + 255) / 256, 256, 0, stream>>>(src, dst, rowptr, cursor, col, NE);

  // ---- L1: agg-first (256 -> 800), relu ----
  gather_kernel<256, 1, 0><<<(NN + 3) / 4, 256, 0, stream>>>(
      x, ns, rowptr, col, nullptr, nullptr, G256, nullptr, NN);
  {
    dim3 g((800 + BN - 1) / BN, (NN + BM - 1) / BM);
    gemm_kernel<<<g, 256, 0, stream>>>(G256, W1, A800, NN, 256, 800, nd, b1, 1);
  }

  // ---- L2: matmul-first (800 -> 128); h2 kept; encoded = sigmoid(h2) ----
  {
    dim3 g((128 + BN - 1) / BN, (NN + BM - 1) / BM);
    gemm_kernel<<<g, 256, 0, stream>>>(A800, W2, T128a, NN, 800, 128, ns, nullptr, 0);
  }
  gather_kernel<128, 0, 1><<<(NN + 7) / 8, 256, 0, stream>>>(
      T128a, nullptr, rowptr, col, nd, b2, T128b, out_enc, NN);

  // ---- L3: agg-first (128 -> 800) on pre-sigmoid h2, relu ----
  gather_kernel<128, 1, 0><<<(NN + 7) / 8, 256, 0, stream>>>(
      T128b, ns, rowptr, col, nullptr, nullptr, T128a, nullptr, NN);
  {
    dim3 g((800 + BN - 1) / BN, (NN + BM - 1) / BM);
    gemm_kernel<<<g, 256, 0, stream>>>(T128a, W3, A800, NN, 128, 800, nd, b3, 1);
  }

  // ---- L4: matmul-first (800 -> 256); decoded = sigmoid ----
  {
    dim3 g((256 + BN - 1) / BN, (NN + BM - 1) / BM);
    gemm_kernel<<<g, 256, 0, stream>>>(A800, W4, G256, NN, 800, 256, ns, nullptr, 0);
  }
  gather_kernel<256, 0, 2><<<(NN + 3) / 4, 256, 0, stream>>>(
      G256, nullptr, rowptr, col, nd, b4, nullptr, out_dec, NN);
}

// Round 3
// 416.312 us; speedup vs baseline: 8.9588x; 1.4987x over previous
//
#include <hip/hip_runtime.h>
#include <math.h>

constexpr int NN = 20000;   // nodes
constexpr int NE = 320000;  // edges
constexpr int MPAD = 20096; // NN padded to 128 for MFMA A-tiles

typedef __bf16 bf16x8 __attribute__((ext_vector_type(8)));
typedef float f32x4 __attribute__((ext_vector_type(4)));

__device__ __forceinline__ unsigned short f2bf(float f) {
  unsigned int u = __float_as_uint(f);
  unsigned int r = (u + 0x7FFFu + ((u >> 16) & 1u)) >> 16;
  return (unsigned short)r;
}

// ---------------- degree count ----------------
__global__ void deg_count_kernel(const int* __restrict__ src, const int* __restrict__ dst,
                                 int* __restrict__ degs, int* __restrict__ degd, int nE) {
  int e = blockIdx.x * blockDim.x + threadIdx.x;
  if (e < nE) {
    atomicAdd(degs + src[e], 1);
    atomicAdd(degd + dst[e], 1);
  }
}

__global__ void norm_kernel(const int* __restrict__ degs, const int* __restrict__ degd,
                            float* __restrict__ ns, float* __restrict__ nd, int n) {
  int i = blockIdx.x * blockDim.x + threadIdx.x;
  if (i < n) {
    ns[i] = rsqrtf(fmaxf((float)degs[i], 1.0f));
    nd[i] = rsqrtf(fmaxf((float)degd[i], 1.0f));
  }
}

// ---------------- single-block exclusive scan -> rowptr ----------------
__global__ __launch_bounds__(1024) void scan_kernel(const int* __restrict__ deg,
                                                    int* __restrict__ rowptr, int n) {
  constexpr int T = 1024;
  const int ITEMS = (n + T - 1) / T;
  __shared__ int sums[T];
  int t = threadIdx.x;
  int base = t * ITEMS;
  int s = 0;
  for (int i = 0; i < ITEMS; ++i) {
    int idx = base + i;
    if (idx < n) s += deg[idx];
  }
  sums[t] = s;
  __syncthreads();
  for (int off = 1; off < T; off <<= 1) {
    int v = (t >= off) ? sums[t - off] : 0;
    __syncthreads();
    sums[t] += v;
    __syncthreads();
  }
  int ex = (t == 0) ? 0 : sums[t - 1];
  for (int i = 0; i < ITEMS; ++i) {
    int idx = base + i;
    if (idx < n) {
      rowptr[idx] = ex;
      ex += deg[idx];
    }
  }
  if (t == 0) rowptr[n] = sums[T - 1];
}

// ---------------- CSR fill ----------------
__global__ void csr_fill_kernel(const int* __restrict__ src, const int* __restrict__ dst,
                                const int* __restrict__ rowptr, int* __restrict__ cursor,
                                int* __restrict__ col, int nE) {
  int e = blockIdx.x * blockDim.x + threadIdx.x;
  if (e < nE) {
    int d = dst[e];
    int p = atomicAdd(cursor + d, 1);
    col[rowptr[d] + p] = src[e];
  }
}

// ---------------- weight convert: W[K][N] f32 -> Wt[Npad][K] bf16 (zero pad) ----------
__global__ void wt_convert_kernel(const float* __restrict__ W, unsigned short* __restrict__ Wt,
                                  int K, int N) {
  int k = blockIdx.x * 256 + threadIdx.x;
  int n = blockIdx.y;
  if (k >= K) return;
  float v = (n < N) ? W[(size_t)k * N + n] : 0.f;
  Wt[(size_t)n * K + k] = f2bf(v);
}

// ---------------- CSR gather aggregation (fp32 in, fp32 or bf16 out) ----------------
// EPI==0: write raw sum. EPI==1: v=sum*sDst+b -> out(f32) AND sigmoid(v)->out2.
// EPI==2: v=sum*sDst+b -> sigmoid(v)->out2 only.
template <int F, int SCALE_SRC, int EPI, int OUT_BF>
__global__ __launch_bounds__(256) void gather_kernel(
    const float* __restrict__ in, const float* __restrict__ sSrc,
    const int* __restrict__ rowptr, const int* __restrict__ col,
    const float* __restrict__ sDst, const float* __restrict__ bias,
    void* __restrict__ out, float* __restrict__ out2, int n) {
  constexpr int F4 = F / 4;
  constexpr int NPB = 256 / F4;
  int tid = threadIdx.x;
  int node = blockIdx.x * NPB + tid / F4;
  int j = tid % F4;
  if (node >= n) return;
  int e0 = rowptr[node], e1 = rowptr[node + 1];
  const float4* in4 = reinterpret_cast<const float4*>(in);
  float4 acc = make_float4(0.f, 0.f, 0.f, 0.f);
  for (int e = e0; e < e1; ++e) {
    int c = col[e];
    float4 v = in4[(size_t)c * F4 + j];
    if (SCALE_SRC) {
      float sc = sSrc[c];
      v.x *= sc; v.y *= sc; v.z *= sc; v.w *= sc;
    }
    acc.x += v.x; acc.y += v.y; acc.z += v.z; acc.w += v.w;
  }
  if (EPI == 0) {
    if (OUT_BF) {
      ushort4 p;
      p.x = f2bf(acc.x); p.y = f2bf(acc.y); p.z = f2bf(acc.z); p.w = f2bf(acc.w);
      reinterpret_cast<ushort4*>(out)[(size_t)node * F4 + j] = p;
    } else {
      reinterpret_cast<float4*>(out)[(size_t)node * F4 + j] = acc;
    }
    return;
  }
  float sd = sDst[node];
  float4 bb = reinterpret_cast<const float4*>(bias)[j];
  acc.x = acc.x * sd + bb.x;
  acc.y = acc.y * sd + bb.y;
  acc.z = acc.z * sd + bb.z;
  acc.w = acc.w * sd + bb.w;
  if (EPI == 1) reinterpret_cast<float4*>(out)[(size_t)node * F4 + j] = acc;
  float4 o;
  o.x = 1.0f / (1.0f + expf(-acc.x));
  o.y = 1.0f / (1.0f + expf(-acc.y));
  o.z = 1.0f / (1.0f + expf(-acc.z));
  o.w = 1.0f / (1.0f + expf(-acc.w));
  reinterpret_cast<float4*>(out2)[(size_t)node * F4 + j] = o;
}

// ---------------- bf16 MFMA GEMM: C[M,N] = epi(A[M,K] @ Wt[N,K]^T) ----------------
// A: bf16 [>=bm+BM_ rows][K]; Wt: bf16 [Npad][K] (transposed weights, Npad%128==0)
// epi: v = acc*rowscale[r] + bias[c]; relu; store bf16 or f32.
// Tile BM_ x 128, BK=32, 4 waves (2x2), per-wave (BM_/2) x 64 via 16x16x32 MFMA.
// LDS swizzle: slot ^= (row>>1)&3 on both the staging SOURCE and the ds_read (rule #21).
template <int BM_, int OUT_BF, int RELU>
__global__ __launch_bounds__(256) void mfma_gemm_kernel(
    const unsigned short* __restrict__ A, const unsigned short* __restrict__ Bt,
    void* __restrict__ C, int M, int K, int N,
    const float* __restrict__ rowscale, const float* __restrict__ bias) {
  constexpr int BN_ = 128, BK_ = 32;
  constexpr int MR = BM_ / 32;        // 16x16 frags per wave in M
  constexpr int CA = BM_ / 64;        // A-stage instrs per wave
  __shared__ __align__(16) unsigned short As[BM_ * BK_];
  __shared__ __align__(16) unsigned short Bs[BN_ * BK_];
  const int tid = threadIdx.x;
  const int w = tid >> 6, l = tid & 63;
  const int wm = w >> 1, wn = w & 1;
  const int bm = blockIdx.y * BM_, bn = blockIdx.x * BN_;
  const int lrow = l & 15, k16 = l >> 4;
  const int slot = l & 3, lr4 = l >> 2;
  const size_t ldb = (size_t)K * 2;   // row stride in bytes (A and Bt share inner dim K)

  f32x4 acc[MR][4] = {};

  for (int k0 = 0; k0 < K; k0 += BK_) {
    const size_t kb = (size_t)(k0 * 2);
#pragma unroll
    for (int j = 0; j < CA; ++j) {
      int chunk = w * CA + j;
      int r0 = chunk * 16 + lr4;
      int gb = (slot ^ ((r0 >> 1) & 3)) << 4;
      const char* gp = (const char*)A + (size_t)(bm + r0) * ldb + kb + gb;
      __builtin_amdgcn_global_load_lds(
          (const __attribute__((address_space(1))) void*)gp,
          (__attribute__((address_space(3))) void*)((char*)As + chunk * 1024), 16, 0, 0);
    }
#pragma unroll
    for (int j = 0; j < 2; ++j) {
      int chunk = w * 2 + j;
      int r0 = chunk * 16 + lr4;
      int gb = (slot ^ ((r0 >> 1) & 3)) << 4;
      const char* gp = (const char*)Bt + (size_t)(bn + r0) * ldb + kb + gb;
      __builtin_amdgcn_global_load_lds(
          (const __attribute__((address_space(1))) void*)gp,
          (__attribute__((address_space(3))) void*)((char*)Bs + chunk * 1024), 16, 0, 0);
    }
    __syncthreads();  // drains vmcnt before barrier -> LDS tiles ready

    bf16x8 bfr[4];
#pragma unroll
    for (int ni = 0; ni < 4; ++ni) {
      int nr = wn * 64 + ni * 16 + lrow;
      bfr[ni] = *reinterpret_cast<const bf16x8*>(&Bs[nr * BK_ + ((k16 ^ ((nr >> 1) & 3)) << 3)]);
    }
#pragma unroll
    for (int mi = 0; mi < MR; ++mi) {
      int r = wm * (BM_ / 2) + mi * 16 + lrow;
      bf16x8 afr = *reinterpret_cast<const bf16x8*>(&As[r * BK_ + ((k16 ^ ((r >> 1) & 3)) << 3)]);
#pragma unroll
      for (int ni = 0; ni < 4; ++ni)
        acc[mi][ni] = __builtin_amdgcn_mfma_f32_16x16x32_bf16(afr, bfr[ni], acc[mi][ni], 0, 0, 0);
    }
    __syncthreads();  // all waves done reading before next stage overwrites
  }

#pragma unroll
  for (int mi = 0; mi < MR; ++mi) {
#pragma unroll
    for (int q = 0; q < 4; ++q) {
      int r = bm + wm * (BM_ / 2) + mi * 16 + (l >> 4) * 4 + q;
      if (r >= M) continue;
      float rs = rowscale ? rowscale[r] : 1.0f;
#pragma unroll
      for (int ni = 0; ni < 4; ++ni) {
        int c = bn + wn * 64 + ni * 16 + lrow;
        if (c >= N) continue;
        float v = acc[mi][ni][q] * rs;
        if (bias) v += bias[c];
        if (RELU) v = fmaxf(v, 0.f);
        if (OUT_BF) ((unsigned short*)C)[(size_t)r * N + c] = f2bf(v);
        else ((float*)C)[(size_t)r * N + c] = v;
      }
    }
  }
}

extern "C" void kernel_launch(void* const* d_in, const int* in_sizes, int n_in,
                              void* d_out, int out_size, void* d_ws, size_t ws_size,
                              hipStream_t stream) {
  const float* x  = (const float*)d_in[0];
  const int* src  = (const int*)d_in[1];
  const int* dst  = (const int*)d_in[2];
  const float* W1 = (const float*)d_in[3];
  const float* b1 = (const float*)d_in[4];
  const float* W2 = (const float*)d_in[5];
  const float* b2 = (const float*)d_in[6];
  const float* W3 = (const float*)d_in[7];
  const float* b3 = (const float*)d_in[8];
  const float* W4 = (const float*)d_in[9];
  const float* b4 = (const float*)d_in[10];

  float* out_enc = (float*)d_out;                  // [NN,128]
  float* out_dec = out_enc + (size_t)NN * 128;     // [NN,256]

  // ---- workspace layout (~92 MB, all chunks 16B-multiples) ----
  float* ns = (float*)d_ws;                        // [NN]
  float* nd = ns + NN;                             // [NN]
  float* T2 = nd + NN;                             // [NN*128]  GEMM2 out (fp32)
  float* h2 = T2 + (size_t)NN * 128;               // [NN*128]  pre-sigmoid encoded
  float* G4 = h2 + (size_t)NN * 128;               // [NN*256]  GEMM4 out (fp32)
  unsigned short* A1  = (unsigned short*)(G4 + (size_t)NN * 256);  // [MPAD*256] bf16
  unsigned short* H1  = A1 + (size_t)MPAD * 256;   // [MPAD*800] bf16 (reused for H3)
  unsigned short* A3  = H1 + (size_t)MPAD * 800;   // [MPAD*128] bf16
  unsigned short* W1t = A3 + (size_t)MPAD * 128;   // [896*256]
  unsigned short* W2t = W1t + 896 * 256;           // [128*800]
  unsigned short* W3t = W2t + 128 * 800;           // [896*128]
  unsigned short* W4t = W3t + 896 * 128;           // [256*800]
  int* degs   = (int*)(W4t + 256 * 800);           // [NN]
  int* degd   = degs + NN;                         // [NN]
  int* cursor = degd + NN;                         // [NN]
  int* rowptr = cursor + NN;                       // [NN+1]
  int* col    = rowptr + NN + 1;                   // [NE]

  // ---- CSR build + norms ----
  hipMemsetAsync(degs, 0, 3 * NN * sizeof(int), stream);
  deg_count_kernel<<<(NE + 255) / 256, 256, 0, stream>>>(src, dst, degs, degd, NE);
  norm_kernel<<<(NN + 255) / 256, 256, 0, stream>>>(degs, degd, ns, nd, NN);
  scan_kernel<<<1, 1024, 0, stream>>>(degd, rowptr, NN);
  csr_fill_kernel<<<(NE + 255) / 256, 256, 0, stream>>>(src, dst, rowptr, cursor, col, NE);

  // ---- weight conversion (transpose + N-pad + bf16) ----
  wt_convert_kernel<<<dim3(1, 896), 256, 0, stream>>>(W1, W1t, 256, 800);
  wt_convert_kernel<<<dim3(4, 128), 256, 0, stream>>>(W2, W2t, 800, 128);
  wt_convert_kernel<<<dim3(1, 896), 256, 0, stream>>>(W3, W3t, 128, 800);
  wt_convert_kernel<<<dim3(4, 256), 256, 0, stream>>>(W4, W4t, 800, 256);

  // ---- L1: gather(x*ns) -> bf16, GEMM1 (256->800) relu -> bf16 ----
  gather_kernel<256, 1, 0, 1><<<(NN + 3) / 4, 256, 0, stream>>>(
      x, ns, rowptr, col, nullptr, nullptr, A1, nullptr, NN);
  mfma_gemm_kernel<128, 1, 1><<<dim3(7, MPAD / 128), 256, 0, stream>>>(
      A1, W1t, H1, NN, 256, 800, nd, b1);

  // ---- L2: GEMM2 (800->128)*ns -> fp32, gather -> h2 + sigmoid(out_enc) ----
  mfma_gemm_kernel<64, 0, 0><<<dim3(1, MPAD / 64), 256, 0, stream>>>(
      H1, W2t, T2, NN, 800, 128, ns, nullptr);
  gather_kernel<128, 0, 1, 0><<<(NN + 7) / 8, 256, 0, stream>>>(
      T2, nullptr, rowptr, col, nd, b2, h2, out_enc, NN);

  // ---- L3: gather(h2*ns) -> bf16, GEMM3 (128->800) relu -> bf16 (reuse H1) ----
  gather_kernel<128, 1, 0, 1><<<(NN + 7) / 8, 256, 0, stream>>>(
      h2, ns, rowptr, col, nullptr, nullptr, A3, nullptr, NN);
  mfma_gemm_kernel<128, 1, 1><<<dim3(7, MPAD / 128), 256, 0, stream>>>(
      A3, W3t, H1, NN, 128, 800, nd, b3);

  // ---- L4: GEMM4 (800->256)*ns -> fp32, gather -> sigmoid(out_dec) ----
  mfma_gemm_kernel<128, 0, 0><<<dim3(2, MPAD / 128), 256, 0, stream>>>(
      H1, W4t, G4, NN, 800, 256, ns, nullptr);
  gather_kernel<256, 0, 2, 0><<<(NN + 3) / 4, 256, 0, stream>>>(
      G4, nullptr, rowptr, col, nd, b4, nullptr, out_dec, NN);
}

// Round 4
// 372.161 us; speedup vs baseline: 10.0217x; 1.1186x over previous
//
#include <hip/hip_runtime.h>
#include <math.h>

constexpr int NN = 20000;   // nodes
constexpr int NE = 320000;  // edges
constexpr int MPAD = 20096; // NN padded to 128

typedef __bf16 bf16x8 __attribute__((ext_vector_type(8)));
typedef float f32x4 __attribute__((ext_vector_type(4)));

__device__ __forceinline__ unsigned short f2bf(float f) {
  unsigned int u = __float_as_uint(f);
  unsigned int r = (u + 0x7FFFu + ((u >> 16) & 1u)) >> 16;
  return (unsigned short)r;
}
__device__ __forceinline__ float bf2f(unsigned short s) {
  return __uint_as_float(((unsigned int)s) << 16);
}

// ---------------- degree count ----------------
__global__ void deg_count_kernel(const int* __restrict__ src, const int* __restrict__ dst,
                                 int* __restrict__ degs, int* __restrict__ degd, int nE) {
  int e = blockIdx.x * blockDim.x + threadIdx.x;
  if (e < nE) {
    atomicAdd(degs + src[e], 1);
    atomicAdd(degd + dst[e], 1);
  }
}

__global__ void norm_kernel(const int* __restrict__ degs, const int* __restrict__ degd,
                            float* __restrict__ ns, float* __restrict__ nd, int n) {
  int i = blockIdx.x * blockDim.x + threadIdx.x;
  if (i < n) {
    ns[i] = rsqrtf(fmaxf((float)degs[i], 1.0f));
    nd[i] = rsqrtf(fmaxf((float)degd[i], 1.0f));
  }
}

// ---------------- single-block exclusive scan -> rowptr ----------------
__global__ __launch_bounds__(1024) void scan_kernel(const int* __restrict__ deg,
                                                    int* __restrict__ rowptr, int n) {
  constexpr int T = 1024;
  const int ITEMS = (n + T - 1) / T;
  __shared__ int sums[T];
  int t = threadIdx.x;
  int base = t * ITEMS;
  int s = 0;
  for (int i = 0; i < ITEMS; ++i) {
    int idx = base + i;
    if (idx < n) s += deg[idx];
  }
  sums[t] = s;
  __syncthreads();
  for (int off = 1; off < T; off <<= 1) {
    int v = (t >= off) ? sums[t - off] : 0;
    __syncthreads();
    sums[t] += v;
    __syncthreads();
  }
  int ex = (t == 0) ? 0 : sums[t - 1];
  for (int i = 0; i < ITEMS; ++i) {
    int idx = base + i;
    if (idx < n) {
      rowptr[idx] = ex;
      ex += deg[idx];
    }
  }
  if (t == 0) rowptr[n] = sums[T - 1];
}

// ---------------- CSR fill ----------------
__global__ void csr_fill_kernel(const int* __restrict__ src, const int* __restrict__ dst,
                                const int* __restrict__ rowptr, int* __restrict__ cursor,
                                int* __restrict__ col, int nE) {
  int e = blockIdx.x * blockDim.x + threadIdx.x;
  if (e < nE) {
    int d = dst[e];
    int p = atomicAdd(cursor + d, 1);
    col[rowptr[d] + p] = src[e];
  }
}

// ---------------- weight convert: W[K][N] f32 -> Wt[Npad][Kpad] bf16 (zero pad) -------
__global__ void wt_convert_kernel(const float* __restrict__ W, unsigned short* __restrict__ Wt,
                                  int K, int N, int Kpad) {
  int k = blockIdx.x * 256 + threadIdx.x;
  int n = blockIdx.y;
  if (k >= Kpad) return;
  float v = (n < N && k < K) ? W[(size_t)k * N + n] : 0.f;
  Wt[(size_t)n * Kpad + k] = f2bf(v);
}

// ---------------- CSR gather aggregation ----------------
// EPI==0: write raw sum. EPI==1: v=sum*sDst+b -> out(f32) AND sigmoid(v)->out2.
// EPI==2: v=sum*sDst+b -> sigmoid(v)->out2 only.
template <int F, int SCALE_SRC, int EPI, int OUT_BF, int IN_BF>
__global__ __launch_bounds__(256) void gather_kernel(
    const void* __restrict__ in, const float* __restrict__ sSrc,
    const int* __restrict__ rowptr, const int* __restrict__ col,
    const float* __restrict__ sDst, const float* __restrict__ bias,
    void* __restrict__ out, float* __restrict__ out2, int n) {
  constexpr int F4 = F / 4;
  constexpr int NPB = 256 / F4;
  int tid = threadIdx.x;
  int node = blockIdx.x * NPB + tid / F4;
  int j = tid % F4;
  if (node >= n) return;
  int e0 = rowptr[node], e1 = rowptr[node + 1];
  float4 acc = make_float4(0.f, 0.f, 0.f, 0.f);
  for (int e = e0; e < e1; ++e) {
    int c = col[e];
    float4 v;
    if (IN_BF) {
      ushort4 u = reinterpret_cast<const ushort4*>(in)[(size_t)c * F4 + j];
      v = make_float4(bf2f(u.x), bf2f(u.y), bf2f(u.z), bf2f(u.w));
    } else {
      v = reinterpret_cast<const float4*>(in)[(size_t)c * F4 + j];
    }
    if (SCALE_SRC) {
      float sc = sSrc[c];
      v.x *= sc; v.y *= sc; v.z *= sc; v.w *= sc;
    }
    acc.x += v.x; acc.y += v.y; acc.z += v.z; acc.w += v.w;
  }
  if (EPI == 0) {
    if (OUT_BF) {
      ushort4 p;
      p.x = f2bf(acc.x); p.y = f2bf(acc.y); p.z = f2bf(acc.z); p.w = f2bf(acc.w);
      reinterpret_cast<ushort4*>(out)[(size_t)node * F4 + j] = p;
    } else {
      reinterpret_cast<float4*>(out)[(size_t)node * F4 + j] = acc;
    }
    return;
  }
  float sd = sDst[node];
  float4 bb = reinterpret_cast<const float4*>(bias)[j];
  acc.x = acc.x * sd + bb.x;
  acc.y = acc.y * sd + bb.y;
  acc.z = acc.z * sd + bb.z;
  acc.w = acc.w * sd + bb.w;
  if (EPI == 1) reinterpret_cast<float4*>(out)[(size_t)node * F4 + j] = acc;
  float4 o;
  o.x = 1.0f / (1.0f + expf(-acc.x));
  o.y = 1.0f / (1.0f + expf(-acc.y));
  o.z = 1.0f / (1.0f + expf(-acc.z));
  o.w = 1.0f / (1.0f + expf(-acc.w));
  reinterpret_cast<float4*>(out2)[(size_t)node * F4 + j] = o;
}

// ---------------- bf16 MFMA GEMM, double-buffered BK=64 pipeline ----------------
// C[M,Npad] = epi(A[M,K] @ Bt[Npad,K]^T), K = NT_*64.
// A,Bt row stride = K elements (bf16). Waves 2x2; per-wave (BM_/2) x 64 output.
// LDS: [2 buffers][(BM_+BN_) rows][64 bf16]; XOR swizzle slot^=(row&7), applied on the
// pre-swizzled global SOURCE address and on the ds_read (rule #21, both-sides).
// Pipeline: stage(t+1) issued BEFORE compute(t); ONE __syncthreads per iter (its
// vmcnt(0) drain lands after compute, so prefetch latency is hidden under MFMA).
// epi: v = acc*rowscale[r] + bias[c]; RELU; ZPAD: cols [Nreal,Npad) stored as 0.
template <int BM_, int BN_, int NT_, int OUT_BF, int RELU, int ZPAD>
__global__ __launch_bounds__(256) void gemm2_kernel(
    const unsigned short* __restrict__ A, const unsigned short* __restrict__ Bt,
    void* __restrict__ C, int M, int Nreal, int Npad,
    const float* __restrict__ rowscale, const float* __restrict__ bias) {
  constexpr int K = NT_ * 64;
  constexpr int MR = BM_ / 32;   // per-wave M frags (wave-grid 2x2)
  constexpr int NR = BN_ / 32;   // per-wave N frags
  constexpr int ROWS = BM_ + BN_;
  __shared__ __align__(16) unsigned short lds[2][ROWS * 64];
  const int tid = threadIdx.x;
  const int w = tid >> 6, l = tid & 63;
  const int wm = w >> 1, wn = w & 1;
  const int bm = blockIdx.y * BM_, bn = blockIdx.x * BN_;
  const int lrow = l & 15, k16 = l >> 4;   // frag row/col, k-slot
  const int lr8 = l >> 3, sl = l & 7;      // staging: row-in-chunk, phys slot

  f32x4 acc[MR][NR] = {};

  auto stage = [&](int buf, int t) {
    const size_t kofs = (size_t)t * 64;
    char* ldsb = (char*)&lds[buf][0];
#pragma unroll
    for (int j = 0; j < BM_ / 32; ++j) {
      int ch = w * (BM_ / 32) + j;
      int r0 = ch * 8 + lr8;
      int gb = (sl ^ (r0 & 7)) << 4;
      const char* gp = (const char*)(A + (size_t)(bm + r0) * K + kofs) + gb;
      __builtin_amdgcn_global_load_lds(
          (const __attribute__((address_space(1))) void*)gp,
          (__attribute__((address_space(3))) void*)(ldsb + ch * 1024), 16, 0, 0);
    }
#pragma unroll
    for (int j = 0; j < BN_ / 32; ++j) {
      int ch = w * (BN_ / 32) + j;
      int r0 = ch * 8 + lr8;
      int gb = (sl ^ (r0 & 7)) << 4;
      const char* gp = (const char*)(Bt + (size_t)(bn + r0) * K + kofs) + gb;
      __builtin_amdgcn_global_load_lds(
          (const __attribute__((address_space(1))) void*)gp,
          (__attribute__((address_space(3))) void*)(ldsb + BM_ * 128 + ch * 1024), 16, 0, 0);
    }
  };

  stage(0, 0);
  __syncthreads();
  for (int t = 0; t < NT_; ++t) {
    const int cur = t & 1;
    if (t + 1 < NT_) stage(cur ^ 1, t + 1);
    const char* ldsb = (const char*)&lds[cur][0];
#pragma unroll
    for (int ks = 0; ks < 2; ++ks) {
      const int s = ks * 4 + k16;  // logical 16B slot within 128B row
      bf16x8 bfr[NR];
#pragma unroll
      for (int ni = 0; ni < NR; ++ni) {
        int br = wn * (BN_ / 2) + ni * 16 + lrow;
        bfr[ni] = *reinterpret_cast<const bf16x8*>(
            ldsb + BM_ * 128 + br * 128 + ((s ^ (br & 7)) << 4));
      }
#pragma unroll
      for (int mi = 0; mi < MR; ++mi) {
        int ar = wm * (BM_ / 2) + mi * 16 + lrow;
        bf16x8 afr = *reinterpret_cast<const bf16x8*>(
            ldsb + ar * 128 + ((s ^ (ar & 7)) << 4));
#pragma unroll
        for (int ni = 0; ni < NR; ++ni)
          acc[mi][ni] = __builtin_amdgcn_mfma_f32_16x16x32_bf16(afr, bfr[ni], acc[mi][ni], 0, 0, 0);
      }
    }
    __syncthreads();  // drains vmcnt(0): prefetch done; all waves done reading buf[cur]
  }

  const int q4 = (l >> 4) * 4;
#pragma unroll
  for (int mi = 0; mi < MR; ++mi) {
#pragma unroll
    for (int q = 0; q < 4; ++q) {
      int r = bm + wm * (BM_ / 2) + mi * 16 + q4 + q;
      if (r >= M) continue;
      float rs = rowscale[r];
#pragma unroll
      for (int ni = 0; ni < NR; ++ni) {
        int c = bn + wn * (BN_ / 2) + ni * 16 + lrow;
        if (ZPAD && c >= Nreal) {
          ((unsigned short*)C)[(size_t)r * Npad + c] = 0;
          continue;
        }
        float v = acc[mi][ni][q] * rs;
        if (bias) v += bias[c];
        if (RELU) v = fmaxf(v, 0.f);
        if (OUT_BF) ((unsigned short*)C)[(size_t)r * Npad + c] = f2bf(v);
        else ((float*)C)[(size_t)r * Npad + c] = v;
      }
    }
  }
}

extern "C" void kernel_launch(void* const* d_in, const int* in_sizes, int n_in,
                              void* d_out, int out_size, void* d_ws, size_t ws_size,
                              hipStream_t stream) {
  const float* x  = (const float*)d_in[0];
  const int* src  = (const int*)d_in[1];
  const int* dst  = (const int*)d_in[2];
  const float* W1 = (const float*)d_in[3];
  const float* b1 = (const float*)d_in[4];
  const float* W2 = (const float*)d_in[5];
  const float* b2 = (const float*)d_in[6];
  const float* W3 = (const float*)d_in[7];
  const float* b3 = (const float*)d_in[8];
  const float* W4 = (const float*)d_in[9];
  const float* b4 = (const float*)d_in[10];

  float* out_enc = (float*)d_out;                  // [NN,128]
  float* out_dec = out_enc + (size_t)NN * 128;     // [NN,256]

  // ---- workspace layout (~85 MB, all chunks 16B multiples) ----
  float* ns = (float*)d_ws;                        // [NN]
  float* nd = ns + NN;                             // [NN]
  float* T2 = nd + NN;                             // [NN*128] f32 (GEMM2 out)
  float* h2 = T2 + (size_t)NN * 128;               // [NN*128] f32 (pre-sigmoid encoded)
  unsigned short* A1  = (unsigned short*)(h2 + (size_t)NN * 128); // [MPAD*256]
  unsigned short* A3  = A1 + (size_t)MPAD * 256;   // [MPAD*128]
  unsigned short* G4  = A3 + (size_t)MPAD * 128;   // [NN*256] bf16 (GEMM4 out)
  unsigned short* H1  = G4 + (size_t)NN * 256;     // [MPAD*896] (GEMM1/3 out, K-padded)
  unsigned short* W1t = H1 + (size_t)MPAD * 896;   // [896*256]
  unsigned short* W2t = W1t + 896 * 256;           // [128*896]
  unsigned short* W3t = W2t + 128 * 896;           // [896*128]
  unsigned short* W4t = W3t + 896 * 128;           // [256*896]
  int* degs   = (int*)(W4t + 256 * 896);           // [NN]
  int* degd   = degs + NN;                         // [NN]
  int* cursor = degd + NN;                         // [NN]
  int* rowptr = cursor + NN;                       // [NN+1]
  int* col    = rowptr + NN + 1;                   // [NE]

  // ---- CSR build + norms ----
  hipMemsetAsync(degs, 0, 3 * NN * sizeof(int), stream);
  deg_count_kernel<<<(NE + 255) / 256, 256, 0, stream>>>(src, dst, degs, degd, NE);
  norm_kernel<<<(NN + 255) / 256, 256, 0, stream>>>(degs, degd, ns, nd, NN);
  scan_kernel<<<1, 1024, 0, stream>>>(degd, rowptr, NN);
  csr_fill_kernel<<<(NE + 255) / 256, 256, 0, stream>>>(src, dst, rowptr, cursor, col, NE);

  // ---- weight conversion (transpose + pad + bf16): Wt[Npad][Kpad] ----
  wt_convert_kernel<<<dim3(1, 896), 256, 0, stream>>>(W1, W1t, 256, 800, 256);
  wt_convert_kernel<<<dim3(4, 128), 256, 0, stream>>>(W2, W2t, 800, 128, 896);
  wt_convert_kernel<<<dim3(1, 896), 256, 0, stream>>>(W3, W3t, 128, 800, 128);
  wt_convert_kernel<<<dim3(4, 256), 256, 0, stream>>>(W4, W4t, 800, 256, 896);

  // ---- L1: gather(x*ns) -> bf16 A1; GEMM1 (K=256 -> N 800/896) relu -> H1 ----
  gather_kernel<256, 1, 0, 1, 0><<<(NN + 3) / 4, 256, 0, stream>>>(
      x, ns, rowptr, col, nullptr, nullptr, A1, nullptr, NN);
  gemm2_kernel<128, 128, 4, 1, 1, 1><<<dim3(7, MPAD / 128), 256, 0, stream>>>(
      A1, W1t, H1, NN, 800, 896, nd, b1);

  // ---- L2: GEMM2 (K=896 -> 128)*ns -> f32 T2; gather -> h2 + sigmoid(out_enc) ----
  gemm2_kernel<64, 128, 14, 0, 0, 0><<<dim3(1, MPAD / 64), 256, 0, stream>>>(
      H1, W2t, T2, NN, 128, 128, ns, nullptr);
  gather_kernel<128, 0, 1, 0, 0><<<(NN + 7) / 8, 256, 0, stream>>>(
      T2, nullptr, rowptr, col, nd, b2, h2, out_enc, NN);

  // ---- L3: gather(h2*ns) -> bf16 A3; GEMM3 (K=128 -> 800/896) relu -> H1 ----
  gather_kernel<128, 1, 0, 1, 0><<<(NN + 7) / 8, 256, 0, stream>>>(
      h2, ns, rowptr, col, nullptr, nullptr, A3, nullptr, NN);
  gemm2_kernel<128, 128, 2, 1, 1, 1><<<dim3(7, MPAD / 128), 256, 0, stream>>>(
      A3, W3t, H1, NN, 800, 896, nd, b3);

  // ---- L4: GEMM4 (K=896 -> 256)*ns -> bf16 G4; gather -> sigmoid(out_dec) ----
  gemm2_kernel<64, 128, 14, 1, 0, 0><<<dim3(2, MPAD / 64), 256, 0, stream>>>(
      H1, W4t, G4, NN, 256, 256, ns, nullptr);
  gather_kernel<256, 0, 2, 0, 1><<<(NN + 3) / 4, 256, 0, stream>>>(
      G4, nullptr, rowptr, col, nd, b4, nullptr, out_dec, NN);
}